// Round 15
// baseline (36.493 us; speedup 1.0000x reference)
//
#include <hip/hip_runtime.h>
#include <hip/hip_bf16.h>
#include <float.h>

// Problem constants (from reference setup_inputs)
#define B_  4
#define C_  256
#define H_  50
#define W_  50
#define R_  300
#define PH_ 7
#define PW_ 7
#define S_  (H_ * W_)        // 2500
#define Q_  (PH_ * PW_)      // 49
#define SC_ (S_ * C_)        // 640000 floats per batch image
#define ARRN (B_ * SC_)      // 2,560,000 floats per table
#define CE_  32              // channels per eighth (= one 128 B line per s)
#define NE_  8               // eighths == XCDs
#define NWG_POOL (R_ * NE_)  // 2400

// ---------------------------------------------------------------------------
// Kernel K1 (e-partitioned): transpose fm [B,C,S] -> fmT [B,S,C] + span
// tables P2 (w..w+1 row-clamped max), P4 (w..w+3).
// Block = (s-tile, eighth): bx = st*8 + e -> hardware round-robin puts
// eighth e on XCD e, so every table line (128 B = one eighth of one s) is
// written INTO the L2 that kernel K2 will read it from. Writes per (s,table)
// are 128 B contiguous, line-exclusive.
// ---------------------------------------------------------------------------
__global__ __launch_bounds__(256) void transpose_tables_e(
    const float* __restrict__ fm,   // [B, C, S]
    float* __restrict__ fmT,        // [B, S, C]
    float* __restrict__ P2,         // [B, S, C]
    float* __restrict__ P4)         // [B, S, C]
{
    __shared__ float tile[CE_][37];          // 32 ch x 35 s-cols (3 halo)

    const int bx = blockIdx.x;               // st*8 + e  (632 = 79*8)
    const int e  = bx & 7;                   // eighth == XCD
    const int st = bx >> 3;                  // s-tile 0..78
    const int b  = blockIdx.y;
    const int s0 = st * 32;
    const int t  = threadIdx.x;              // 0..255

    // load: 32 channels x up to 35 s-cols (35-float runs, coalesced-ish)
    for (int idx = t; idx < CE_ * 35; idx += 256) {
        const int c  = idx / 35;
        const int ls = idx - c * 35;
        const int s  = s0 + ls;
        if (s < S_)
            tile[c][ls] = fm[(b * C_ + e * CE_ + c) * S_ + s];
    }
    __syncthreads();

    // store: 32 s x 32 ch, c fastest -> 128 B contiguous per (s, table).
    // LDS read bank = (37c + ls) % 32 = (5c + ls) % 32, gcd(5,32)=1 -> clean.
    const int c   = t & 31;
    const int ls0 = t >> 5;                  // 0..7
    #pragma unroll
    for (int j = 0; j < 4; ++j) {
        const int ls = ls0 + j * 8;          // 0..31
        const int s  = s0 + ls;
        if (s < S_) {
            const int w = s % W_;
            int rem = W_ - 1 - w;            // valid same-row neighbors
            if (rem > 3) rem = 3;
            const float v0 = tile[c][ls];    // halo slots ls+d (d<=rem) are
            float p2 = (rem >= 1) ? fmaxf(v0, tile[c][ls + 1]) : v0;  // loaded:
            float p4 = p2;                   // s+rem < row end < S_
            if (rem >= 2) p4 = fmaxf(p4, tile[c][ls + 2]);
            if (rem >= 3) p4 = fmaxf(p4, tile[c][ls + 3]);

            const int o = (b * S_ + s) * C_ + e * CE_ + c;   // int32-safe
            fmT[o] = v0;
            P2[o]  = p2;
            P4[o]  = p4;
        }
    }
}

// ---------------------------------------------------------------------------
// Block-uniform ROI decode (SPATIAL_SCALE == 1.0); matches reference exactly.
// ---------------------------------------------------------------------------
__device__ __forceinline__ void roi_decode(const float* __restrict__ rois, int r,
                                           int& b, int& x0, int& y0,
                                           int& roi_w, int& roi_h)
{
    const float* rp = rois + r * 5;
    b = (int)rp[4];                          // trunc, matches astype(int32)
    // jnp.round == round-half-to-even == rintf
    x0      = (int)rintf(rp[0]);
    y0      = (int)rintf(rp[1]);
    int x1  = (int)rintf(rp[2]);
    int y1  = (int)rintf(rp[3]);
    x0 = min(max(x0, 0), W_ - 1);
    x1 = min(max(x1, 0), W_ - 1);
    y0 = min(max(y0, 0), H_ - 1);
    y1 = min(max(y1, 0), H_ - 1);
    x1 = max(x1, x0 + 1);
    y1 = max(y1, y0 + 1);
    roi_w = x1 - x0;                         // >= 1  (bin widths  <= 8)
    roi_h = y1 - y0;                         // >= 1  (bin heights <= 8)
}

// ---------------------------------------------------------------------------
// Per-bin pooling, R10's serial structure (4 waves x 13 bins), lane =
// (channel c in 0..31, anchor half). Span tables: sp=4/2/1 -> anchors ws and
// we-sp union EXACTLY to [ws,we) for any ww 1..8 (proven R7-R10). Rows:
// min(hs+kh, he-1) in-window clamp. Cross-half combine via shfl_xor(32).
// Wave q-ranges: w0 0-12, w1 13-24, w2 25-36, w3 37-48 (clamp re-computes
// own last bin; same value, no cross-wave aliasing).
// ---------------------------------------------------------------------------
template<int WH>
__device__ __forceinline__ void pool_bins_e(
    const float* __restrict__ fmT, const float* __restrict__ P2,
    const float* __restrict__ P4, float* __restrict__ buf,
    int wv, int lane, int imgCE,
    int x0, int y0, int roi_w, int roi_h)
{
    const int c    = lane & 31;
    const int half = lane >> 5;
    const int start = wv * 12 + (wv ? 1 : 0);
    const int qlast = wv * 12 + 12;

    #pragma unroll 2
    for (int k = 0; k < 13; ++k) {
        int q = start + k;
        q = (q > qlast) ? qlast : q;
        const int ph = q / PW_;
        const int pw = q - ph * PW_;
        const int ws = x0 + (pw * roi_w) / PW_;
        const int we = x0 + ((pw + 1) * roi_w + PW_ - 1) / PW_;
        const int hs = y0 + (ph * roi_h) / PH_;
        const int he = y0 + ((ph + 1) * roi_h + PH_ - 1) / PH_;
        const int ww = we - ws;              // 1..8

        const int sp = (ww >= 4) ? 4 : ((ww >= 2) ? 2 : 1);
        const float* tb = (ww >= 4) ? P4 : ((ww >= 2) ? P2 : fmT);
        const int col = (half ? (we - sp) : ws) * C_;   // per-lane anchor

        float va[WH];
        #pragma unroll
        for (int kh = 0; kh < WH; ++kh) {
            int row = hs + kh;
            row = (row > he - 1) ? (he - 1) : row;      // clamp (in-window)
            va[kh] = tb[imgCE + row * (W_ * C_) + col];
        }
        float m = -FLT_MAX;
        #pragma unroll
        for (int kh = 0; kh < WH; ++kh)
            m = fmaxf(m, va[kh]);

        m = fmaxf(m, __shfl_xor(m, 32));     // combine anchor halves
        if (half == 0)
            buf[q * 33 + c] = m;
    }
}

// ---------------------------------------------------------------------------
// Kernel K2: block = (roi, eighth) -> 2400 blocks, 256 threads (4 waves).
// e = bid & 7 -> XCD e serves channel slice e for ALL ROIs: per-XCD table
// footprint 3 x 1.28 MB = 3.84 MB < 4 MB L2, lines 128 B-exact per eighth.
// Output written with NONTEMPORAL stores so the 15 MB stream doesn't evict
// the resident tables. Block-exclusive contiguous 6272 B write.
// ---------------------------------------------------------------------------
__global__ __launch_bounds__(256) void roi_pool_e(
    const float* __restrict__ fmT,   // [B, S, C]
    const float* __restrict__ P2,    // [B, S, C]
    const float* __restrict__ P4,    // [B, S, C]
    const float* __restrict__ rois,  // [R, 5]
    float* __restrict__ out)         // [R, C, Q]
{
    __shared__ float buf[Q_ * 33];           // 6468 B

    const int bid = blockIdx.x;
    const int e   = bid & 7;                 // eighth == XCD (round-robin)
    const int r   = bid >> 3;                // roi

    const int t    = threadIdx.x;
    const int wv   = t >> 6;                 // wave 0..3
    const int lane = t & 63;

    int b, x0, y0, roi_w, roi_h;
    roi_decode(rois, r, b, x0, y0, roi_w, roi_h);

    // exact block-uniform max bin height
    int whmax = 1;
    #pragma unroll
    for (int i = 0; i < PH_; ++i) {
        const int hs = (i * roi_h) / PH_;
        const int he = ((i + 1) * roi_h + PH_ - 1) / PH_;
        whmax = max(whmax, he - hs);
    }

    const int imgCE = b * SC_ + e * CE_ + (lane & 31);   // int32-safe

    switch (whmax) {                         // block-uniform dispatch
        case 1: pool_bins_e<1>(fmT, P2, P4, buf, wv, lane, imgCE, x0, y0, roi_w, roi_h); break;
        case 2: pool_bins_e<2>(fmT, P2, P4, buf, wv, lane, imgCE, x0, y0, roi_w, roi_h); break;
        case 3: pool_bins_e<3>(fmT, P2, P4, buf, wv, lane, imgCE, x0, y0, roi_w, roi_h); break;
        case 4: pool_bins_e<4>(fmT, P2, P4, buf, wv, lane, imgCE, x0, y0, roi_w, roi_h); break;
        case 5: pool_bins_e<5>(fmT, P2, P4, buf, wv, lane, imgCE, x0, y0, roi_w, roi_h); break;
        case 6: pool_bins_e<6>(fmT, P2, P4, buf, wv, lane, imgCE, x0, y0, roi_w, roi_h); break;
        case 7: pool_bins_e<7>(fmT, P2, P4, buf, wv, lane, imgCE, x0, y0, roi_w, roi_h); break;
        default: pool_bins_e<8>(fmT, P2, P4, buf, wv, lane, imgCE, x0, y0, roi_w, roi_h); break;
    }
    __syncthreads();

    // block-exclusive write: out[r, e*32 .. e*32+32, 0..49) = 6272 B,
    // nontemporal (streaming, no L2 pollution of the resident tables).
    float* outp = out + ((size_t)r * C_ + e * CE_) * Q_;
    #pragma unroll
    for (int k = 0; k < 7; ++k) {            // ceil(32*49 / 256) = 7
        const int idx = k * 256 + t;
        if (idx < CE_ * Q_) {
            const int cl = idx / Q_;
            const int q  = idx - cl * Q_;
            __builtin_nontemporal_store(buf[q * 33 + cl], &outp[idx]);
        }
    }
}

// ---------------------------------------------------------------------------
// Fallback (ws too small): round-1 thread-per-output kernel (proven, 42.7 us).
// ---------------------------------------------------------------------------
__global__ __launch_bounds__(256) void roi_pool_naive(
    const float* __restrict__ fm,    // [B, C, H, W]
    const float* __restrict__ rois,
    float* __restrict__ out)
{
    const int total = R_ * C_ * Q_;
    int t = blockIdx.x * blockDim.x + threadIdx.x;
    if (t >= total) return;
    int q   = t % Q_;
    int tmp = t / Q_;
    int pw  = q % PW_;
    int ph  = q / PW_;
    int c   = tmp % C_;
    int r   = tmp / C_;

    int b, x0, y0, roi_w, roi_h;
    roi_decode(rois, r, b, x0, y0, roi_w, roi_h);

    const int ws = x0 + (pw * roi_w) / PW_;
    const int we = x0 + ((pw + 1) * roi_w + PW_ - 1) / PW_;
    const int hs = y0 + (ph * roi_h) / PH_;
    const int he = y0 + ((ph + 1) * roi_h + PH_ - 1) / PH_;

    const float* p = fm + ((size_t)(b * C_ + c)) * S_;
    float m = -FLT_MAX;
    for (int h = hs; h < he; ++h)
        for (int w = ws; w < we; ++w)
            m = fmaxf(m, p[h * W_ + w]);
    out[t] = m;
}

extern "C" void kernel_launch(void* const* d_in, const int* in_sizes, int n_in,
                              void* d_out, int out_size, void* d_ws, size_t ws_size,
                              hipStream_t stream)
{
    const float* fm   = (const float*)d_in[0];  // [4,256,50,50]
    const float* rois = (const float*)d_in[1];  // [300,5]
    float* out        = (float*)d_out;          // [300,256,7,7]

    const size_t NEED = 3 * (size_t)ARRN * sizeof(float);   // 30.72 MB

    if (ws_size >= NEED) {
        float* fmT = (float*)d_ws;
        float* P2  = fmT + ARRN;
        float* P4  = P2 + ARRN;
        {
            dim3 grid(79 * NE_, B_);             // (632, 4): (s-tile, eighth) x batch
            transpose_tables_e<<<grid, 256, 0, stream>>>(fm, fmT, P2, P4);
        }
        roi_pool_e<<<NWG_POOL, 256, 0, stream>>>(fmT, P2, P4, rois, out);
    } else {
        const int total = R_ * C_ * Q_;
        roi_pool_naive<<<(total + 255) / 256, 256, 0, stream>>>(fm, rois, out);
    }
}